// Round 9
// baseline (366.051 us; speedup 1.0000x reference)
//
#include <hip/hip_runtime.h>
#include <hip/hip_bf16.h>
#include <stdint.h>
#include <stddef.h>

// Problem constants
#define B_ 32
#define N_ 1024
#define C_ 768
#define H_ 12
#define D_ 64
#define M_ (B_*N_)     // 32768 rows
#define TC_ (3*C_)     // 2304 qkv cols

typedef __bf16 bf16_t;
typedef __attribute__((ext_vector_type(8))) __bf16 bf16x8;
typedef __attribute__((ext_vector_type(4))) __bf16 bf16x4;
typedef __attribute__((ext_vector_type(4))) float  f32x4;

#define MFMA16(a,b,c) __builtin_amdgcn_mfma_f32_16x16x32_bf16(a,b,c,0,0,0)

__device__ __forceinline__ void lds_load16(const void* g, void* l) {
  __builtin_amdgcn_global_load_lds(
      (const __attribute__((address_space(1))) void*)g,
      (__attribute__((address_space(3))) void*)l, 16, 0, 0);
}

// raw global load -> 4 VGPRs; landing guaranteed by explicit counted vmcnt
__device__ __forceinline__ bf16x8 gload16(const bf16_t* p) {
  bf16x8 r;
  asm volatile("global_load_dwordx4 %0, %1, off" : "=v"(r) : "v"(p));
  return r;
}

// ---------------------------------------------------------------- converts
__global__ void cvt_bf16(const float* __restrict__ in, bf16_t* __restrict__ out, int n) {
  int i = (blockIdx.x * 256 + threadIdx.x) * 8;
  if (i >= n) return;
  const float4 a = *(const float4*)(in + i);
  const float4 b = *(const float4*)(in + i + 4);
  bf16x8 r;
  r[0]=(bf16_t)a.x; r[1]=(bf16_t)a.y; r[2]=(bf16_t)a.z; r[3]=(bf16_t)a.w;
  r[4]=(bf16_t)b.x; r[5]=(bf16_t)b.y; r[6]=(bf16_t)b.z; r[7]=(bf16_t)b.w;
  *(bf16x8*)(out + i) = r;
}

// out[c][r] = bf16(in[r][c]); grid (Cc/32, R/32), 256 threads
__global__ void transpose_cvt(const float* __restrict__ in, bf16_t* __restrict__ out,
                              int R, int Cc) {
  __shared__ float t[32][33];
  const int c0 = blockIdx.x * 32, r0 = blockIdx.y * 32;
  const int tx = threadIdx.x & 31, ty = threadIdx.x >> 5;  // ty 0..7
  #pragma unroll
  for (int k = 0; k < 4; ++k)
    t[ty + k*8][tx] = in[(size_t)(r0 + ty + k*8)*Cc + c0 + tx];
  __syncthreads();
  #pragma unroll
  for (int k = 0; k < 4; ++k)
    out[(size_t)(c0 + ty + k*8)*R + r0 + tx] = (bf16_t)t[tx][ty + k*8];
}

// ---------------------------------------------------------------- GEMM 256x256, BK=32, 8 waves
// A: LDS ring of 3 x 16KB (48KB), staged depth 2 via global_load_lds, with the
//    QUARTER-WAVE-correct XOR swizzle: phys16Bchunk = logchunk ^ ((row>>1)&3)
//    (bank group = (4*fr + chunk) mod 8 -> fr=0..7 cover all 8 groups, 2 lanes
//    each = free 2-way). DMA dest linear; global SOURCE pre-swizzled (rule 21).
// B: never in LDS. Register double-buffer (bsa/bsb), 4 asm global_load_dwordx4
//    per wave per tile from L2-resident weights, prefetch distance 1.
// vmcnt audit (per-tile issue: B x4 then A-DMA x2): head wait = vmcnt(2)
//    guarantees A(t),B(t) landed with A(t+1) in flight; t=23 drains vmcnt(0).
// Wave tile 128x64 (2Mx4N waves). K = 768 = 24 tiles.
// MODE 1: qkv scatter epilogue (q -> (b,h,n,d); k,v -> (b,h,d,n)), bf16 + bias
// MODE 3: out projection; A = qh gathered as (b*1024+n, h*64+d); fp32 out + bias;
//         BT per-batch stride 768*768.
template<int MODE>
__global__ __launch_bounds__(512)
void gemm_bt(const bf16_t* __restrict__ A, const bf16_t* __restrict__ BT,
             const float* __restrict__ bias, float* __restrict__ Cout,
             bf16_t* __restrict__ qh,
             bf16_t* __restrict__ kthi, bf16_t* __restrict__ vthi,
             int nbx)
{
  __shared__ __align__(16) char smem[49152];

  const int nwg = gridDim.x;
  const int cpx = nwg >> 3;                       // nwg % 8 == 0
  const int bid = blockIdx.x;
  const int swz = (bid & 7) * cpx + (bid >> 3);   // bijective XCD chunking
  const int bx  = swz % nbx;
  const int by  = swz / nbx;

  const int tid  = threadIdx.x;
  const int wave = tid >> 6;
  const int lane = tid & 63;
  const int rowBase = by * 256;
  const int colBase = bx * 256;
  const int wr = wave >> 2;          // 0..1  (row block of 128)
  const int wc = wave & 3;           // 0..3  (col block of 64)
  const int fr = lane & 15;
  const int hi = lane >> 4;          // 0..3  (8-elem k-group)
  const int b   = rowBase >> 10;     // batch (256-row tile inside one batch)
  const int nn0 = rowBase & (N_ - 1);

  // A staging source: thread covers LDS row (tid>>2), phys chunk (tid&3);
  // source logical chunk = (tid&3) ^ ((row>>1)&3) = (tid&3) ^ ((tid>>3)&3).
  const int srow = tid >> 2;         // 0..127
  const int scol = (((tid & 3) ^ ((tid >> 3) & 3)) << 3);
  const bf16_t *Ap0, *Ap1;
  if (MODE == 3) {
    Ap0 = A + (size_t)b * (H_*N_*D_) + (size_t)(nn0 + srow) * D_ + scol;
    Ap1 = Ap0 + (size_t)128 * D_;
  } else {
    Ap0 = A + (size_t)(rowBase + srow) * 768 + scol;
    Ap1 = Ap0 + (size_t)128 * 768;
  }

  // B register-buffer source pointers (advance 32 elems per tile)
  const bf16_t *Bq0, *Bq1, *Bq2, *Bq3;
  {
    const size_t bts = (MODE == 3) ? (size_t)b * C_ * C_ : 0;
    const int bcol = colBase + wc*64 + fr;
    const int ko = hi * 8;
    Bq0 = BT + bts + (size_t)(bcol +  0)*768 + ko;
    Bq1 = BT + bts + (size_t)(bcol + 16)*768 + ko;
    Bq2 = BT + bts + (size_t)(bcol + 32)*768 + ko;
    Bq3 = BT + bts + (size_t)(bcol + 48)*768 + ko;
  }

  // A fragment read: row r = wr*128 + m*16 + fr, phys chunk = hi ^ ((fr>>1)&3)
  const int chxA = ((hi ^ ((fr >> 1) & 3)) << 4);
  const int aoff = (wr*128 + fr)*64 + chxA;          // + m*1024

#define RDA(BI,MM) (*(const bf16x8*)(smem + (BI)*16384 + aoff + (MM)*1024))

#define A_OFF(K0) ((MODE == 3) ? ((size_t)((K0) >> 6) << 16) + ((K0) & 32) : (size_t)(K0))

#define STAGE_A(BI, T) do {                                                   \
    const int k0_ = (T) * 32;                                                 \
    const size_t ao_ = A_OFF(k0_);                                            \
    lds_load16(Ap0 + ao_, smem + (BI)*16384 + tid*16);                        \
    lds_load16(Ap1 + ao_, smem + (BI)*16384 + 8192 + tid*16);                 \
  } while (0)

#define BLOAD(NS) do {                                                        \
    NS##0 = gload16(Bq0); NS##1 = gload16(Bq1);                               \
    NS##2 = gload16(Bq2); NS##3 = gload16(Bq3);                               \
    Bq0 += 32; Bq1 += 32; Bq2 += 32; Bq3 += 32;                               \
  } while (0)

  bf16x8 bsa0, bsa1, bsa2, bsa3;
  bf16x8 bsb0, bsb1, bsb2, bsb3;

  f32x4 acc[8][4];
  #pragma unroll
  for (int m = 0; m < 8; ++m)
    #pragma unroll
    for (int n = 0; n < 4; ++n) acc[m][n] = f32x4{0.f,0.f,0.f,0.f};

#define MFMA_HALF(CS, MB)                                                     \
    acc[MB+0][0]=MFMA16(a0_,CS##0,acc[MB+0][0]); acc[MB+0][1]=MFMA16(a0_,CS##1,acc[MB+0][1]); \
    acc[MB+0][2]=MFMA16(a0_,CS##2,acc[MB+0][2]); acc[MB+0][3]=MFMA16(a0_,CS##3,acc[MB+0][3]); \
    acc[MB+1][0]=MFMA16(a1_,CS##0,acc[MB+1][0]); acc[MB+1][1]=MFMA16(a1_,CS##1,acc[MB+1][1]); \
    acc[MB+1][2]=MFMA16(a1_,CS##2,acc[MB+1][2]); acc[MB+1][3]=MFMA16(a1_,CS##3,acc[MB+1][3]); \
    acc[MB+2][0]=MFMA16(a2_,CS##0,acc[MB+2][0]); acc[MB+2][1]=MFMA16(a2_,CS##1,acc[MB+2][1]); \
    acc[MB+2][2]=MFMA16(a2_,CS##2,acc[MB+2][2]); acc[MB+2][3]=MFMA16(a2_,CS##3,acc[MB+2][3]); \
    acc[MB+3][0]=MFMA16(a3_,CS##0,acc[MB+3][0]); acc[MB+3][1]=MFMA16(a3_,CS##1,acc[MB+3][1]); \
    acc[MB+3][2]=MFMA16(a3_,CS##2,acc[MB+3][2]); acc[MB+3][3]=MFMA16(a3_,CS##3,acc[MB+3][3]);

#define TILE(BI, NBI, CS, NS, T, DOB, DOA, VM) do {                           \
    asm volatile("s_waitcnt vmcnt(" #VM ")" ::: "memory");                    \
    __builtin_amdgcn_sched_barrier(0);                                        \
    __builtin_amdgcn_s_barrier();                                             \
    __builtin_amdgcn_sched_barrier(0);                                        \
    if (DOB) { BLOAD(NS); }                                                   \
    __builtin_amdgcn_sched_barrier(0);                                        \
    if (DOA) { STAGE_A(NBI, (T)+2); }                                         \
    __builtin_amdgcn_sched_barrier(0);                                        \
    bf16x8 a0_=RDA(BI,0), a1_=RDA(BI,1), a2_=RDA(BI,2), a3_=RDA(BI,3);        \
    asm volatile("s_waitcnt lgkmcnt(0)" ::: "memory");                        \
    __builtin_amdgcn_sched_barrier(0);                                        \
    __builtin_amdgcn_s_setprio(1);                                            \
    MFMA_HALF(CS, 0)                                                          \
    __builtin_amdgcn_s_setprio(0);                                            \
    a0_=RDA(BI,4); a1_=RDA(BI,5); a2_=RDA(BI,6); a3_=RDA(BI,7);               \
    asm volatile("s_waitcnt lgkmcnt(0)" ::: "memory");                        \
    __builtin_amdgcn_sched_barrier(0);                                        \
    __builtin_amdgcn_s_setprio(1);                                            \
    MFMA_HALF(CS, 4)                                                          \
    __builtin_amdgcn_s_setprio(0);                                            \
    __builtin_amdgcn_sched_barrier(0);                                        \
  } while (0)

  // prologue: B(0) -> bsa (4 loads); A(0) -> buf0, A(1) -> buf1 (4 DMA)
  BLOAD(bsa);
  STAGE_A(0, 0);
  STAGE_A(1, 1);

  #pragma unroll 1
  for (int it = 0; it < 3; ++it) {
    const int tb = it * 6;
    TILE(0, 2, bsa, bsb, tb+0, 1, 1, 2);
    TILE(1, 0, bsb, bsa, tb+1, 1, 1, 2);
    TILE(2, 1, bsa, bsb, tb+2, 1, 1, 2);
    TILE(0, 2, bsb, bsa, tb+3, 1, 1, 2);
    TILE(1, 0, bsa, bsb, tb+4, 1, 1, 2);
    TILE(2, 1, bsb, bsa, tb+5, 1, 1, 2);
  }
  TILE(0, 2, bsa, bsb, 18, 1, 1, 2);
  TILE(1, 0, bsb, bsa, 19, 1, 1, 2);
  TILE(2, 1, bsa, bsb, 20, 1, 1, 2);
  TILE(0, 2, bsb, bsa, 21, 1, 1, 2);   // stages A(23) -> buf2
  TILE(1, 0, bsa, bsb, 22, 1, 0, 2);   // loads B(23) -> bsb
  TILE(2, 1, bsb, bsa, 23, 0, 0, 0);

#undef TILE
#undef MFMA_HALF
#undef BLOAD
#undef STAGE_A
#undef A_OFF
#undef RDA

  // ---------------------------------------------------------------- epilogue
  // C/D frag layout: row = wr*128 + m*16 + (lane>>4)*4 + j, col = wc*64 + n*16 + fr
  if (MODE == 3) {
    #pragma unroll
    for (int n = 0; n < 4; ++n) {
      const int gc = colBase + wc*64 + n*16 + fr;
      const float bb = bias[gc];
      #pragma unroll
      for (int m = 0; m < 8; ++m) {
        const int gr = rowBase + wr*128 + m*16 + ((lane >> 4) << 2);
        #pragma unroll
        for (int j = 0; j < 4; ++j)
          Cout[(size_t)(gr + j)*C_ + gc] = acc[m][n][j] + bb;
      }
    }
  } else {
    __syncthreads();                       // main-loop LDS dead; reuse
    bf16_t* tile = (bf16_t*)smem;          // [64 cols][pitch 260 rows] = 33.3 KB
    const int s = colBase / C_;            // 0=q 1=k 2=v (uniform per block)
    #pragma unroll 1
    for (int ch = 0; ch < 4; ++ch) {       // 64-col chunks of the 256-wide block
      if (ch) __syncthreads();
      if (wc == ch) {
        #pragma unroll
        for (int n = 0; n < 4; ++n) {
          const int cl = n*16 + fr;                        // 0..63
          const float bb = bias[colBase + ch*64 + cl];
          #pragma unroll
          for (int m = 0; m < 8; ++m) {
            const int r0 = wr*128 + m*16 + ((lane >> 4) << 2);
            bf16x4 hv;
            hv[0]=(bf16_t)(acc[m][n][0]+bb); hv[1]=(bf16_t)(acc[m][n][1]+bb);
            hv[2]=(bf16_t)(acc[m][n][2]+bb); hv[3]=(bf16_t)(acc[m][n][3]+bb);
            *(bf16x4*)&tile[cl*260 + r0] = hv;
          }
        }
      }
      __syncthreads();
      const int gcol0 = colBase + ch*64;
      if (s == 0) {
        // q: row-major (b,h,n,d); chunk = exactly one head
        const int h = gcol0 >> 6;
        const int r = tid >> 1, hh = tid & 1;
        bf16_t* dst = qh + (((size_t)b*H_ + h)*N_ + nn0 + r)*D_ + hh*32;
        #pragma unroll
        for (int i0 = 0; i0 < 32; i0 += 8) {
          bf16x8 vv;
          #pragma unroll
          for (int i = 0; i < 8; ++i) vv[i] = tile[(hh*32 + i0 + i)*260 + r];
          *(bf16x8*)&dst[i0] = vv;
        }
      } else {
        // k/v: (b,h,d,n); chunk = one head, d = col-local
        const int rem = gcol0 - s*C_;
        const int h = rem >> 6;
        const int d = tid >> 3, nq = (tid & 7)*32;
        bf16_t* dst = (s == 1 ? kthi : vthi)
                      + (((size_t)b*H_ + h)*D_ + d)*N_ + nn0 + nq;
        #pragma unroll
        for (int i0 = 0; i0 < 32; i0 += 8)
          *(bf16x8*)&dst[i0] = *(const bf16x8*)&tile[d*260 + nq + i0];
      }
    }
  }
}

// ---------------------------------------------------------------- stage 2: logits + softmax
// attnT[bh][e][d] = P[d][e], P = softmax_e( sum_n kt[d][n]*vt[e][n] / 8 )
__global__ __launch_bounds__(256, 2)
void attn_softmax_k(const bf16_t* __restrict__ kthi, const bf16_t* __restrict__ vthi,
                    bf16_t* __restrict__ attnT)
{
  __shared__ float tile[64][65];
  __shared__ float invs[64];
  const int bh = blockIdx.x;
  const int tid = threadIdx.x, wave = tid >> 6, lane = tid & 63;
  const int fr = lane & 15, fo = (lane >> 4) * 8;
  const size_t base = (size_t)bh * D_ * N_;
  f32x4 acc[4][4] = {{0.f,0.f,0.f,0.f}};
  const int k0lo = wave * 256;   // split-K across 4 waves
  #pragma unroll 1
  for (int k0 = k0lo; k0 < k0lo + 256; k0 += 32) {
    bf16x8 ah[4], bhv[4];
    #pragma unroll
    for (int m = 0; m < 4; ++m)
      ah[m] = *(const bf16x8*)&kthi[base + (size_t)(m*16 + fr)*N_ + k0 + fo];
    #pragma unroll
    for (int n = 0; n < 4; ++n)
      bhv[n] = *(const bf16x8*)&vthi[base + (size_t)(n*16 + fr)*N_ + k0 + fo];
    #pragma unroll
    for (int m = 0; m < 4; ++m)
      #pragma unroll
      for (int n = 0; n < 4; ++n)
        acc[m][n] = MFMA16(ah[m], bhv[n], acc[m][n]);
  }
  // cross-wave reduce into LDS
  for (int w = 0; w < 4; ++w) {
    if (wave == w) {
      #pragma unroll
      for (int m = 0; m < 4; ++m)
        #pragma unroll
        for (int n = 0; n < 4; ++n) {
          const int row = m*16 + ((lane >> 4) << 2);
          const int col = n*16 + fr;
          #pragma unroll
          for (int j = 0; j < 4; ++j) {
            if (w == 0) tile[row+j][col]  = acc[m][n][j];
            else        tile[row+j][col] += acc[m][n][j];
          }
        }
    }
    __syncthreads();
  }
  // row softmax (scale 1/8), one thread per row d
  if (tid < 64) {
    float mx = -3.0e38f;
    #pragma unroll
    for (int c = 0; c < 64; ++c) mx = fmaxf(mx, tile[tid][c]);
    mx *= 0.125f;
    float ssum = 0.f;
    #pragma unroll
    for (int c = 0; c < 64; ++c) {
      const float ev = __expf(tile[tid][c]*0.125f - mx);
      tile[tid][c] = ev;
      ssum += ev;
    }
    invs[tid] = 1.0f / ssum;
  }
  __syncthreads();
  // transposed write: thread e writes attnT[e][0..63] contiguous
  if (tid < 64) {
    bf16_t* ao = attnT + (size_t)bh * D_ * D_ + tid * D_;
    #pragma unroll
    for (int d0 = 0; d0 < 64; d0 += 8) {
      bf16x8 vv;
      #pragma unroll
      for (int i = 0; i < 8; ++i) vv[i] = (bf16_t)(tile[d0+i][tid] * invs[d0+i]);
      *(bf16x8*)&ao[d0] = vv;
    }
  }
}

// ---------------------------------------------------------------- stage 3: W' compose
// w2t[b][j][h*64+e] = sum_d woutT[j][h*64+d] * attnT[bh][e][d]
// grid (6, B*H), 256 threads (4 waves x 32 j-rows each)
__global__ __launch_bounds__(256, 2)
void compose_w2(const bf16_t* __restrict__ woutT, const bf16_t* __restrict__ attnT,
                bf16_t* __restrict__ w2t)
{
  const int jb = blockIdx.x;
  const int bh = blockIdx.y;
  const int b = bh / H_, h = bh - b*H_;
  const int tid = threadIdx.x, wave = tid >> 6, lane = tid & 63;
  const int fr = lane & 15, fo = (lane >> 4) * 8;
  const bf16_t* at = attnT + (size_t)bh * D_ * D_;
  f32x4 acc[2][4] = {{0.f,0.f,0.f,0.f}};
  #pragma unroll
  for (int kk = 0; kk < 2; ++kk) {
    bf16x8 af[2], bfv[4];
    #pragma unroll
    for (int m = 0; m < 2; ++m)
      af[m] = *(const bf16x8*)&woutT[(size_t)(jb*128 + wave*32 + m*16 + fr)*C_ + h*64 + kk*32 + fo];
    #pragma unroll
    for (int n = 0; n < 4; ++n)
      bfv[n] = *(const bf16x8*)&at[(n*16 + fr)*64 + kk*32 + fo];
    #pragma unroll
    for (int m = 0; m < 2; ++m)
      #pragma unroll
      for (int n = 0; n < 4; ++n)
        acc[m][n] = MFMA16(af[m], bfv[n], acc[m][n]);
  }
  bf16_t* wb = w2t + (size_t)b * C_ * C_;
  #pragma unroll
  for (int m = 0; m < 2; ++m) {
    const int j = jb*128 + wave*32 + m*16 + ((lane >> 4) << 2);
    #pragma unroll
    for (int n = 0; n < 4; ++n) {
      const int e = n*16 + fr;
      #pragma unroll
      for (int jj = 0; jj < 4; ++jj)
        wb[(size_t)(j + jj)*C_ + h*64 + e] = (bf16_t)acc[m][n][jj];
    }
  }
}

// ---------------------------------------------------------------- launcher
extern "C" void kernel_launch(void* const* d_in, const int* in_sizes, int n_in,
                              void* d_out, int out_size, void* d_ws, size_t ws_size,
                              hipStream_t stream)
{
  (void)in_sizes; (void)n_in; (void)out_size;
  const float* x     = (const float*)d_in[0];
  const float* w_qkv = (const float*)d_in[1];
  const float* b_qkv = (const float*)d_in[2];
  const float* w_out = (const float*)d_in[3];
  const float* b_out = (const float*)d_in[4];
  float* out = (float*)d_out;

  const size_t sz_xb   = (size_t)M_*C_*2;        // 50.3 MB
  const size_t sz_wq   = (size_t)TC_*C_*2;       //  3.5 MB
  const size_t sz_wo   = (size_t)C_*C_*2;        //  1.2 MB
  const size_t sz_qh   = (size_t)B_*H_*N_*D_*2;  // 50.3 MB
  const size_t sz_kv   = (size_t)B_*H_*D_*N_*2;  // 50.3 MB each
  const size_t sz_attn = (size_t)B_*H_*D_*D_*2;  //  3.1 MB

  char* p = (char*)d_ws;
  bf16_t* xb    = (bf16_t*)p; p += sz_xb;
  bf16_t* wqkvT = (bf16_t*)p; p += sz_wq;
  bf16_t* woutT = (bf16_t*)p; p += sz_wo;
  bf16_t* qh    = (bf16_t*)p; p += sz_qh;
  bf16_t* kthi  = (bf16_t*)p; p += sz_kv;
  bf16_t* vthi  = (bf16_t*)p; p += sz_kv;
  bf16_t* attnT = (bf16_t*)p; p += sz_attn;
  const size_t base_need = (size_t)(p - (char*)d_ws);
  // W' (32 x 768 x 768 bf16 = 37.7 MB) aliases xb (50.3 MB), dead after GEMM1
  bf16_t* w2t = xb;

  if (ws_size < base_need) return;   // leaves poison -> distinctive failure

  cvt_bf16<<<dim3((M_*C_)/2048), 256, 0, stream>>>(x, xb, M_*C_);
  transpose_cvt<<<dim3(TC_/32, C_/32), 256, 0, stream>>>(w_qkv, wqkvT, C_, TC_);
  transpose_cvt<<<dim3(C_/32,  C_/32), 256, 0, stream>>>(w_out, woutT, C_, C_);

  // GEMM1: qkv projection with scatter epilogue. grid = 9 x 128 = 1152 (8 | 1152)
  gemm_bt<1><<<dim3((TC_/256)*(M_/256)), 512, 0, stream>>>(
      xb, wqkvT, b_qkv, nullptr, qh, kthi, vthi, TC_/256);

  attn_softmax_k<<<dim3(B_*H_), 256, 0, stream>>>(kthi, vthi, attnT);

  compose_w2<<<dim3(C_/128, B_*H_), 256, 0, stream>>>(woutT, attnT, w2t);

  // GEMM2: out = qh(gathered) @ W'_b + b_out. grid = 3 x 128 = 384 (8 | 384)
  gemm_bt<3><<<dim3((C_/256)*(M_/256)), 512, 0, stream>>>(
      qh, w2t, b_out, out, nullptr, nullptr, nullptr, C_/256);
}

// Round 10
// 308.703 us; speedup vs baseline: 1.1858x; 1.1858x over previous
//
#include <hip/hip_runtime.h>
#include <hip/hip_bf16.h>
#include <stdint.h>
#include <stddef.h>

// Problem constants
#define B_ 32
#define N_ 1024
#define C_ 768
#define H_ 12
#define D_ 64
#define M_ (B_*N_)     // 32768 rows
#define TC_ (3*C_)     // 2304 qkv cols

typedef __bf16 bf16_t;
typedef __attribute__((ext_vector_type(8))) __bf16 bf16x8;
typedef __attribute__((ext_vector_type(4))) __bf16 bf16x4;
typedef __attribute__((ext_vector_type(4))) float  f32x4;

#define MFMA16(a,b,c) __builtin_amdgcn_mfma_f32_16x16x32_bf16(a,b,c,0,0,0)

__device__ __forceinline__ void lds_load16(const void* g, void* l) {
  __builtin_amdgcn_global_load_lds(
      (const __attribute__((address_space(1))) void*)g,
      (__attribute__((address_space(3))) void*)l, 16, 0, 0);
}

// ---------------------------------------------------------------- converts
__global__ void cvt_bf16(const float* __restrict__ in, bf16_t* __restrict__ out, int n) {
  int i = (blockIdx.x * 256 + threadIdx.x) * 8;
  if (i >= n) return;
  const float4 a = *(const float4*)(in + i);
  const float4 b = *(const float4*)(in + i + 4);
  bf16x8 r;
  r[0]=(bf16_t)a.x; r[1]=(bf16_t)a.y; r[2]=(bf16_t)a.z; r[3]=(bf16_t)a.w;
  r[4]=(bf16_t)b.x; r[5]=(bf16_t)b.y; r[6]=(bf16_t)b.z; r[7]=(bf16_t)b.w;
  *(bf16x8*)(out + i) = r;
}

// out[c][r] = bf16(in[r][c]); grid (Cc/32, R/32), 256 threads
__global__ void transpose_cvt(const float* __restrict__ in, bf16_t* __restrict__ out,
                              int R, int Cc) {
  __shared__ float t[32][33];
  const int c0 = blockIdx.x * 32, r0 = blockIdx.y * 32;
  const int tx = threadIdx.x & 31, ty = threadIdx.x >> 5;  // ty 0..7
  #pragma unroll
  for (int k = 0; k < 4; ++k)
    t[ty + k*8][tx] = in[(size_t)(r0 + ty + k*8)*Cc + c0 + tx];
  __syncthreads();
  #pragma unroll
  for (int k = 0; k < 4; ++k)
    out[(size_t)(c0 + ty + k*8)*R + r0 + tx] = (bf16_t)t[tx][ty + k*8];
}

// ---------------------------------------------------------------- GEMM 256x256, BK=32, 8 waves
// R5's 4-buffer ring (4 x 32KB, prefetch depth 3, counted boundary vmcnt(8), tail 8/8/4/0)
// + QUARTER-WAVE-CORRECT XOR swizzle (R9-verified, conflicts 1.14e7 -> 7.9e5):
//   phys16Bchunk = logchunk ^ ((row>>1)&3)
//   stage:  LDS dest linear (DMA); global source col-chunk = (tid&3) ^ ((tid>>3)&3)
//   read:   phys chunk = (lane>>4) ^ ((fr>>1)&3)  (valid for A and B rows alike)
// Bank audit: quarter-wave quad = 4*(fr&1) + phys -> 8 quads x 2 lanes = free.
// Wave tile 128x64 (2Mx4N waves). K = 768 = 24 tiles.
// MODE 1: qkv scatter epilogue (q -> (b,h,n,d); k,v -> (b,h,d,n)), bf16 + bias
// MODE 3: out projection; A = qh gathered as (b*1024+n, h*64+d); fp32 out + bias;
//         BT per-batch stride 768*768.
template<int MODE>
__global__ __launch_bounds__(512, 2)
void gemm_bt(const bf16_t* __restrict__ A, const bf16_t* __restrict__ BT,
             const float* __restrict__ bias, float* __restrict__ Cout,
             bf16_t* __restrict__ qh,
             bf16_t* __restrict__ kthi, bf16_t* __restrict__ vthi,
             int nbx)
{
  __shared__ __align__(16) char smem[131072];

  const int nwg = gridDim.x;
  const int cpx = nwg >> 3;                       // nwg % 8 == 0
  const int bid = blockIdx.x;
  const int swz = (bid & 7) * cpx + (bid >> 3);   // bijective XCD chunking
  const int bx  = swz % nbx;
  const int by  = swz / nbx;

  const int tid  = threadIdx.x;
  const int wave = tid >> 6;
  const int lane = tid & 63;
  const int rowBase = by * 256;
  const int colBase = bx * 256;
  const int wr = wave >> 2;          // 0..1  (row block of 128)
  const int wc = wave & 3;           // 0..3  (col block of 64)
  const int fr = lane & 15;
  const int b   = rowBase >> 10;     // batch (256-row tile inside one batch)
  const int nn0 = rowBase & (N_ - 1);

  // Staging: thread covers LDS row (tid>>2), phys chunk (tid&3);
  // source logical chunk = (tid&3) ^ ((row>>1)&3) = (tid&3) ^ ((tid>>3)&3).
  const int srow = tid >> 2;         // 0..127
  const int scol = (((tid & 3) ^ ((tid >> 3) & 3)) << 3);   // swizzled source elems
  const bf16_t *Ap0, *Ap1, *Bp0, *Bp1;
  if (MODE == 3) {
    Ap0 = A + (size_t)b * (H_*N_*D_) + (size_t)(nn0 + srow) * D_ + scol;
    Ap1 = Ap0 + (size_t)128 * D_;
    const size_t bts = (size_t)b * C_ * C_;
    Bp0 = BT + bts + (size_t)(colBase + srow) * 768 + scol;
    Bp1 = Bp0 + (size_t)128 * 768;
  } else {
    Ap0 = A + (size_t)(rowBase + srow) * 768 + scol;
    Ap1 = Ap0 + (size_t)128 * 768;
    Bp0 = BT + (size_t)(colBase + srow) * 768 + scol;
    Bp1 = Bp0 + (size_t)128 * 768;
  }

  // fragment read byte offsets; phys chunk = hi ^ ((fr>>1)&3)
  const int chxA = (((lane >> 4) ^ ((fr >> 1) & 3)) << 4);
  const int aoff = (wr*128 + fr)*64 + chxA;          // + m*1024
  const int boff = 16384 + (wc*64 + fr)*64 + chxA;   // + n*1024

#define RDA(BI,MM) (*(const bf16x8*)(smem + (BI)*32768 + aoff + (MM)*1024))
#define RDB(BI,NN) (*(const bf16x8*)(smem + (BI)*32768 + boff + (NN)*1024))

#define A_OFF(K0) ((MODE == 3) ? ((size_t)((K0) >> 6) << 16) + ((K0) & 32) : (size_t)(K0))

#define STAGE_A(BI, T) do {                                                   \
    const int k0_ = (T) * 32;                                                 \
    const size_t ao_ = A_OFF(k0_);                                            \
    lds_load16(Ap0 + ao_, smem + (BI)*32768 + tid*16);                        \
    lds_load16(Ap1 + ao_, smem + (BI)*32768 + 8192 + tid*16);                 \
  } while (0)

#define STAGE_B(BI, T) do {                                                   \
    const int k0_ = (T) * 32;                                                 \
    lds_load16(Bp0 + k0_, smem + (BI)*32768 + 16384 + tid*16);                \
    lds_load16(Bp1 + k0_, smem + (BI)*32768 + 24576 + tid*16);                \
  } while (0)

  f32x4 acc[8][4];
  #pragma unroll
  for (int m = 0; m < 8; ++m)
    #pragma unroll
    for (int n = 0; n < 4; ++n) acc[m][n] = f32x4{0.f,0.f,0.f,0.f};

#define MFMA_HALF(MB)                                                         \
    acc[MB+0][0]=MFMA16(a0_,b0_,acc[MB+0][0]); acc[MB+0][1]=MFMA16(a0_,b1_,acc[MB+0][1]); \
    acc[MB+0][2]=MFMA16(a0_,b2_,acc[MB+0][2]); acc[MB+0][3]=MFMA16(a0_,b3_,acc[MB+0][3]); \
    acc[MB+1][0]=MFMA16(a1_,b0_,acc[MB+1][0]); acc[MB+1][1]=MFMA16(a1_,b1_,acc[MB+1][1]); \
    acc[MB+1][2]=MFMA16(a1_,b2_,acc[MB+1][2]); acc[MB+1][3]=MFMA16(a1_,b3_,acc[MB+1][3]); \
    acc[MB+2][0]=MFMA16(a2_,b0_,acc[MB+2][0]); acc[MB+2][1]=MFMA16(a2_,b1_,acc[MB+2][1]); \
    acc[MB+2][2]=MFMA16(a2_,b2_,acc[MB+2][2]); acc[MB+2][3]=MFMA16(a2_,b3_,acc[MB+2][3]); \
    acc[MB+3][0]=MFMA16(a3_,b0_,acc[MB+3][0]); acc[MB+3][1]=MFMA16(a3_,b1_,acc[MB+3][1]); \
    acc[MB+3][2]=MFMA16(a3_,b2_,acc[MB+3][2]); acc[MB+3][3]=MFMA16(a3_,b3_,acc[MB+3][3]);

#define TILE(BI, T, DOST, VM) do {                                            \
    asm volatile("s_waitcnt vmcnt(" #VM ")" ::: "memory");                    \
    __builtin_amdgcn_sched_barrier(0);                                        \
    __builtin_amdgcn_s_barrier();                                             \
    __builtin_amdgcn_sched_barrier(0);                                        \
    if (DOST) { STAGE_A(((BI)+3)&3, (T)+3); }                                 \
    __builtin_amdgcn_sched_barrier(0);                                        \
    bf16x8 b0_=RDB(BI,0), b1_=RDB(BI,1), b2_=RDB(BI,2), b3_=RDB(BI,3);        \
    bf16x8 a0_=RDA(BI,0), a1_=RDA(BI,1), a2_=RDA(BI,2), a3_=RDA(BI,3);        \
    __builtin_amdgcn_s_setprio(1);                                            \
    MFMA_HALF(0)                                                              \
    __builtin_amdgcn_s_setprio(0);                                            \
    if (DOST) { STAGE_B(((BI)+3)&3, (T)+3); }                                 \
    __builtin_amdgcn_sched_barrier(0);                                        \
    a0_=RDA(BI,4); a1_=RDA(BI,5); a2_=RDA(BI,6); a3_=RDA(BI,7);               \
    __builtin_amdgcn_s_setprio(1);                                            \
    MFMA_HALF(4)                                                              \
    __builtin_amdgcn_s_setprio(0);                                            \
    asm volatile("s_waitcnt lgkmcnt(0)" ::: "memory");                        \
    __builtin_amdgcn_sched_barrier(0);                                        \
  } while (0)

  // prologue: stage tiles 0,1,2 into buffers 0,1,2 (12 loads/thread in flight)
  STAGE_A(0,0); STAGE_B(0,0);
  STAGE_A(1,1); STAGE_B(1,1);
  STAGE_A(2,2); STAGE_B(2,2);

  #pragma unroll 1
  for (int t = 0; t < 20; t += 4) {
    TILE(0, t,   1, 8);
    TILE(1, t+1, 1, 8);
    TILE(2, t+2, 1, 8);
    TILE(3, t+3, 1, 8);
  }
  TILE(0, 20, 1, 8);   // stages tile 23
  TILE(1, 21, 0, 8);
  TILE(2, 22, 0, 4);
  TILE(3, 23, 0, 0);

#undef TILE
#undef MFMA_HALF
#undef STAGE_A
#undef STAGE_B
#undef A_OFF
#undef RDA
#undef RDB

  // ---------------------------------------------------------------- epilogue
  // C/D frag layout: row = wr*128 + m*16 + (lane>>4)*4 + j, col = wc*64 + n*16 + fr
  if (MODE == 3) {
    #pragma unroll
    for (int n = 0; n < 4; ++n) {
      const int gc = colBase + wc*64 + n*16 + fr;
      const float bb = bias[gc];
      #pragma unroll
      for (int m = 0; m < 8; ++m) {
        const int gr = rowBase + wr*128 + m*16 + ((lane >> 4) << 2);
        #pragma unroll
        for (int j = 0; j < 4; ++j)
          Cout[(size_t)(gr + j)*C_ + gc] = acc[m][n][j] + bb;
      }
    }
  } else {
    __syncthreads();                       // main-loop LDS dead; reuse
    bf16_t* tile = (bf16_t*)smem;          // [64 cols][pitch 260 rows] = 33.3 KB
    const int s = colBase / C_;            // 0=q 1=k 2=v (uniform per block)
    #pragma unroll 1
    for (int ch = 0; ch < 4; ++ch) {       // 64-col chunks of the 256-wide block
      if (ch) __syncthreads();
      if (wc == ch) {
        #pragma unroll
        for (int n = 0; n < 4; ++n) {
          const int cl = n*16 + fr;                        // 0..63
          const float bb = bias[colBase + ch*64 + cl];
          #pragma unroll
          for (int m = 0; m < 8; ++m) {
            const int r0 = wr*128 + m*16 + ((lane >> 4) << 2);
            bf16x4 hv;
            hv[0]=(bf16_t)(acc[m][n][0]+bb); hv[1]=(bf16_t)(acc[m][n][1]+bb);
            hv[2]=(bf16_t)(acc[m][n][2]+bb); hv[3]=(bf16_t)(acc[m][n][3]+bb);
            *(bf16x4*)&tile[cl*260 + r0] = hv;
          }
        }
      }
      __syncthreads();
      const int gcol0 = colBase + ch*64;
      if (s == 0) {
        // q: row-major (b,h,n,d); chunk = exactly one head
        const int h = gcol0 >> 6;
        const int r = tid >> 1, hh = tid & 1;
        bf16_t* dst = qh + (((size_t)b*H_ + h)*N_ + nn0 + r)*D_ + hh*32;
        #pragma unroll
        for (int i0 = 0; i0 < 32; i0 += 8) {
          bf16x8 vv;
          #pragma unroll
          for (int i = 0; i < 8; ++i) vv[i] = tile[(hh*32 + i0 + i)*260 + r];
          *(bf16x8*)&dst[i0] = vv;
        }
      } else {
        // k/v: (b,h,d,n); chunk = one head, d = col-local
        const int rem = gcol0 - s*C_;
        const int h = rem >> 6;
        const int d = tid >> 3, nq = (tid & 7)*32;
        bf16_t* dst = (s == 1 ? kthi : vthi)
                      + (((size_t)b*H_ + h)*D_ + d)*N_ + nn0 + nq;
        #pragma unroll
        for (int i0 = 0; i0 < 32; i0 += 8)
          *(bf16x8*)&dst[i0] = *(const bf16x8*)&tile[d*260 + nq + i0];
      }
    }
  }
}

// ---------------------------------------------------------------- stage 2: logits + softmax
// attnT[bh][e][d] = P[d][e], P = softmax_e( sum_n kt[d][n]*vt[e][n] / 8 )
__global__ __launch_bounds__(256, 2)
void attn_softmax_k(const bf16_t* __restrict__ kthi, const bf16_t* __restrict__ vthi,
                    bf16_t* __restrict__ attnT)
{
  __shared__ float tile[64][65];
  __shared__ float invs[64];
  const int bh = blockIdx.x;
  const int tid = threadIdx.x, wave = tid >> 6, lane = tid & 63;
  const int fr = lane & 15, fo = (lane >> 4) * 8;
  const size_t base = (size_t)bh * D_ * N_;
  f32x4 acc[4][4] = {{0.f,0.f,0.f,0.f}};
  const int k0lo = wave * 256;   // split-K across 4 waves
  #pragma unroll 1
  for (int k0 = k0lo; k0 < k0lo + 256; k0 += 32) {
    bf16x8 ah[4], bhv[4];
    #pragma unroll
    for (int m = 0; m < 4; ++m)
      ah[m] = *(const bf16x8*)&kthi[base + (size_t)(m*16 + fr)*N_ + k0 + fo];
    #pragma unroll
    for (int n = 0; n < 4; ++n)
      bhv[n] = *(const bf16x8*)&vthi[base + (size_t)(n*16 + fr)*N_ + k0 + fo];
    #pragma unroll
    for (int m = 0; m < 4; ++m)
      #pragma unroll
      for (int n = 0; n < 4; ++n)
        acc[m][n] = MFMA16(ah[m], bhv[n], acc[m][n]);
  }
  // cross-wave reduce into LDS
  for (int w = 0; w < 4; ++w) {
    if (wave == w) {
      #pragma unroll
      for (int m = 0; m < 4; ++m)
        #pragma unroll
        for (int n = 0; n < 4; ++n) {
          const int row = m*16 + ((lane >> 4) << 2);
          const int col = n*16 + fr;
          #pragma unroll
          for (int j = 0; j < 4; ++j) {
            if (w == 0) tile[row+j][col]  = acc[m][n][j];
            else        tile[row+j][col] += acc[m][n][j];
          }
        }
    }
    __syncthreads();
  }
  // row softmax (scale 1/8), one thread per row d
  if (tid < 64) {
    float mx = -3.0e38f;
    #pragma unroll
    for (int c = 0; c < 64; ++c) mx = fmaxf(mx, tile[tid][c]);
    mx *= 0.125f;
    float ssum = 0.f;
    #pragma unroll
    for (int c = 0; c < 64; ++c) {
      const float ev = __expf(tile[tid][c]*0.125f - mx);
      tile[tid][c] = ev;
      ssum += ev;
    }
    invs[tid] = 1.0f / ssum;
  }
  __syncthreads();
  // transposed write: thread e writes attnT[e][0..63] contiguous
  if (tid < 64) {
    bf16_t* ao = attnT + (size_t)bh * D_ * D_ + tid * D_;
    #pragma unroll
    for (int d0 = 0; d0 < 64; d0 += 8) {
      bf16x8 vv;
      #pragma unroll
      for (int i = 0; i < 8; ++i) vv[i] = (bf16_t)(tile[d0+i][tid] * invs[d0+i]);
      *(bf16x8*)&ao[d0] = vv;
    }
  }
}

// ---------------------------------------------------------------- stage 3: W' compose
// w2t[b][j][h*64+e] = sum_d woutT[j][h*64+d] * attnT[bh][e][d]
// grid (6, B*H), 256 threads (4 waves x 32 j-rows each)
__global__ __launch_bounds__(256, 2)
void compose_w2(const bf16_t* __restrict__ woutT, const bf16_t* __restrict__ attnT,
                bf16_t* __restrict__ w2t)
{
  const int jb = blockIdx.x;
  const int bh = blockIdx.y;
  const int b = bh / H_, h = bh - b*H_;
  const int tid = threadIdx.x, wave = tid >> 6, lane = tid & 63;
  const int fr = lane & 15, fo = (lane >> 4) * 8;
  const bf16_t* at = attnT + (size_t)bh * D_ * D_;
  f32x4 acc[2][4] = {{0.f,0.f,0.f,0.f}};
  #pragma unroll
  for (int kk = 0; kk < 2; ++kk) {
    bf16x8 af[2], bfv[4];
    #pragma unroll
    for (int m = 0; m < 2; ++m)
      af[m] = *(const bf16x8*)&woutT[(size_t)(jb*128 + wave*32 + m*16 + fr)*C_ + h*64 + kk*32 + fo];
    #pragma unroll
    for (int n = 0; n < 4; ++n)
      bfv[n] = *(const bf16x8*)&at[(n*16 + fr)*64 + kk*32 + fo];
    #pragma unroll
    for (int m = 0; m < 2; ++m)
      #pragma unroll
      for (int n = 0; n < 4; ++n)
        acc[m][n] = MFMA16(af[m], bfv[n], acc[m][n]);
  }
  bf16_t* wb = w2t + (size_t)b * C_ * C_;
  #pragma unroll
  for (int m = 0; m < 2; ++m) {
    const int j = jb*128 + wave*32 + m*16 + ((lane >> 4) << 2);
    #pragma unroll
    for (int n = 0; n < 4; ++n) {
      const int e = n*16 + fr;
      #pragma unroll
      for (int jj = 0; jj < 4; ++jj)
        wb[(size_t)(j + jj)*C_ + h*64 + e] = (bf16_t)acc[m][n][jj];
    }
  }
}

// ---------------------------------------------------------------- launcher
extern "C" void kernel_launch(void* const* d_in, const int* in_sizes, int n_in,
                              void* d_out, int out_size, void* d_ws, size_t ws_size,
                              hipStream_t stream)
{
  (void)in_sizes; (void)n_in; (void)out_size;
  const float* x     = (const float*)d_in[0];
  const float* w_qkv = (const float*)d_in[1];
  const float* b_qkv = (const float*)d_in[2];
  const float* w_out = (const float*)d_in[3];
  const float* b_out = (const float*)d_in[4];
  float* out = (float*)d_out;

  const size_t sz_xb   = (size_t)M_*C_*2;        // 50.3 MB
  const size_t sz_wq   = (size_t)TC_*C_*2;       //  3.5 MB
  const size_t sz_wo   = (size_t)C_*C_*2;        //  1.2 MB
  const size_t sz_qh   = (size_t)B_*H_*N_*D_*2;  // 50.3 MB
  const size_t sz_kv   = (size_t)B_*H_*D_*N_*2;  // 50.3 MB each
  const size_t sz_attn = (size_t)B_*H_*D_*D_*2;  //  3.1 MB

  char* p = (char*)d_ws;
  bf16_t* xb    = (bf16_t*)p; p += sz_xb;
  bf16_t* wqkvT = (bf16_t*)p; p += sz_wq;
  bf16_t* woutT = (bf16_t*)p; p += sz_wo;
  bf16_t* qh    = (bf16_t*)p; p += sz_qh;
  bf16_t* kthi  = (bf16_t*)p; p += sz_kv;
  bf16_t* vthi  = (bf16_t*)p; p += sz_kv;
  bf16_t* attnT = (bf16_t*)p; p += sz_attn;
  const size_t base_need = (size_t)(p - (char*)d_ws);
  // W' (32 x 768 x 768 bf16 = 37.7 MB) aliases xb (50.3 MB), dead after GEMM1
  bf16_t* w2t = xb;

  if (ws_size < base_need) return;   // leaves poison -> distinctive failure

  cvt_bf16<<<dim3((M_*C_)/2048), 256, 0, stream>>>(x, xb, M_*C_);
  transpose_cvt<<<dim3(TC_/32, C_/32), 256, 0, stream>>>(w_qkv, wqkvT, C_, TC_);
  transpose_cvt<<<dim3(C_/32,  C_/32), 256, 0, stream>>>(w_out, woutT, C_, C_);

  // GEMM1: qkv projection with scatter epilogue. grid = 9 x 128 = 1152 (8 | 1152)
  gemm_bt<1><<<dim3((TC_/256)*(M_/256)), 512, 0, stream>>>(
      xb, wqkvT, b_qkv, nullptr, qh, kthi, vthi, TC_/256);

  attn_softmax_k<<<dim3(B_*H_), 256, 0, stream>>>(kthi, vthi, attnT);

  compose_w2<<<dim3(C_/128, B_*H_), 256, 0, stream>>>(woutT, attnT, w2t);

  // GEMM2: out = qh(gathered) @ W'_b + b_out. grid = 3 x 128 = 384 (8 | 384)
  gemm_bt<3><<<dim3((C_/256)*(M_/256)), 512, 0, stream>>>(
      qh, w2t, b_out, out, nullptr, nullptr, nullptr, C_/256);
}

// Round 11
// 302.153 us; speedup vs baseline: 1.2115x; 1.0217x over previous
//
#include <hip/hip_runtime.h>
#include <hip/hip_bf16.h>
#include <stdint.h>
#include <stddef.h>

// Problem constants
#define B_ 32
#define N_ 1024
#define C_ 768
#define H_ 12
#define D_ 64
#define M_ (B_*N_)     // 32768 rows
#define TC_ (3*C_)     // 2304 qkv cols

typedef __bf16 bf16_t;
typedef __attribute__((ext_vector_type(8))) __bf16 bf16x8;
typedef __attribute__((ext_vector_type(4))) __bf16 bf16x4;
typedef __attribute__((ext_vector_type(4))) float  f32x4;

#define MFMA16(a,b,c) __builtin_amdgcn_mfma_f32_16x16x32_bf16(a,b,c,0,0,0)

__device__ __forceinline__ void lds_load16(const void* g, void* l) {
  __builtin_amdgcn_global_load_lds(
      (const __attribute__((address_space(1))) void*)g,
      (__attribute__((address_space(3))) void*)l, 16, 0, 0);
}

// ---------------------------------------------------------------- converts
__global__ void cvt_bf16(const float* __restrict__ in, bf16_t* __restrict__ out, int n) {
  int i = (blockIdx.x * 256 + threadIdx.x) * 8;
  if (i >= n) return;
  const float4 a = *(const float4*)(in + i);
  const float4 b = *(const float4*)(in + i + 4);
  bf16x8 r;
  r[0]=(bf16_t)a.x; r[1]=(bf16_t)a.y; r[2]=(bf16_t)a.z; r[3]=(bf16_t)a.w;
  r[4]=(bf16_t)b.x; r[5]=(bf16_t)b.y; r[6]=(bf16_t)b.z; r[7]=(bf16_t)b.w;
  *(bf16x8*)(out + i) = r;
}

// out[c][r] = bf16(in[r][c]); grid (Cc/32, R/32), 256 threads
__global__ void transpose_cvt(const float* __restrict__ in, bf16_t* __restrict__ out,
                              int R, int Cc) {
  __shared__ float t[32][33];
  const int c0 = blockIdx.x * 32, r0 = blockIdx.y * 32;
  const int tx = threadIdx.x & 31, ty = threadIdx.x >> 5;  // ty 0..7
  #pragma unroll
  for (int k = 0; k < 4; ++k)
    t[ty + k*8][tx] = in[(size_t)(r0 + ty + k*8)*Cc + c0 + tx];
  __syncthreads();
  #pragma unroll
  for (int k = 0; k < 4; ++k)
    out[(size_t)(c0 + ty + k*8)*R + r0 + tx] = (bf16_t)t[tx][ty + k*8];
}

// ---------------------------------------------------------------- GEMM 256x256, BK=64, 8 waves
// m201-style 8-phase schedule. 2 double-buffers (2 x 64KB): per buf A[2 half][128][64],
// B[2 half][128][64]; rows 128B = 8 chunks; swizzle phys = log ^ (row&7) (R7/R10-verified).
// Per phase: {4 ds_read A-quad (+8 B at tile head, held in regs) | stage 1 half-tile |
//   bar | lgkm0 | setprio(1) 16 MFMA setprio(0) | [vmcnt(4) at P3/P7] bar}.
// Stage ledger (iter i, tiles t0=2i buf0, t0+1 buf1):
//   P0: A-h0(t0+1)    P1: A-h1(t0+1), B-h0(t0+2)   P2: B-h1(t0+2)   P3: - [vmcnt4]
//   P4: A-h0(t0+2)    P5: A-h1(t0+2)               P6: B-h0(t0+3)   P7: B-h1(t0+3) [vmcnt4]
// B region dead after P0-end barrier, A after P3-end (quadrants consume rows progressively).
// MODE 1: qkv scatter epilogue (q -> (b,h,n,d); k,v -> (b,h,d,n)), bf16 + bias
// MODE 3: out projection; A = qh gathered (K-tile T == head T, contiguous); fp32 out + bias.
template<int MODE>
__global__ __launch_bounds__(512, 2)
void gemm_bt(const bf16_t* __restrict__ A, const bf16_t* __restrict__ BT,
             const float* __restrict__ bias, float* __restrict__ Cout,
             bf16_t* __restrict__ qh,
             bf16_t* __restrict__ kthi, bf16_t* __restrict__ vthi,
             int nbx)
{
  __shared__ __align__(16) char smem[131072];

  const int nwg = gridDim.x;
  const int cpx = nwg >> 3;                       // nwg % 8 == 0
  const int bid = blockIdx.x;
  const int swz = (bid & 7) * cpx + (bid >> 3);   // bijective XCD chunking
  const int bx  = swz % nbx;
  const int by  = swz / nbx;

  const int tid  = threadIdx.x;
  const int wave = tid >> 6;
  const int lane = tid & 63;
  const int rowBase = by * 256;
  const int colBase = bx * 256;
  const int wr = wave >> 2;          // 0..1  (row block of 128)
  const int wc = wave & 3;           // 0..3  (col block of 64)
  const int fr = lane & 15;
  const int hi = lane >> 4;          // 0..3  (8-elem k-subgroup)
  const int b   = rowBase >> 10;
  const int nn0 = rowBase & (N_ - 1);

  // ---- staging mapping: thread t -> half-tile row rls=(t>>3)(+64j), phys chunk t&7;
  // source logical col-chunk = (t&7)^((t>>3)&7) (row&7 invariant under +64).
  const int rls  = tid >> 3;
  const int scol = (((tid & 7) ^ ((tid >> 3) & 7)) << 3);
  const bf16_t *ApS0, *ApS1, *BpS0, *BpS1;
  size_t AKT, AJS;                           // A: per-K-tile step, j(+64 rows) step
  if (MODE == 3) {
    const bf16_t* ab = A + (size_t)b * (H_*N_*D_);
    ApS0 = ab + (size_t)(nn0 + rls) * D_ + scol;
    ApS1 = ab + (size_t)(nn0 + 128 + rls) * D_ + scol;
    AKT = (size_t)N_ * D_;  AJS = (size_t)64 * D_;
  } else {
    ApS0 = A + (size_t)(rowBase + rls) * 768 + scol;
    ApS1 = A + (size_t)(rowBase + 128 + rls) * 768 + scol;
    AKT = 64;  AJS = (size_t)64 * 768;
  }
  const size_t bts = (MODE == 3) ? (size_t)b * C_ * C_ : 0;
  BpS0 = BT + bts + (size_t)(colBase + rls) * 768 + scol;
  BpS1 = BT + bts + (size_t)(colBase + 128 + rls) * 768 + scol;
  const size_t BJS = (size_t)64 * 768;

  // ---- fragment read offsets: phys chunk = (kk*4+hi) ^ (fr&7); rows 128 B.
  const int axr  = fr & 7;
  const int chx0 = ((0 + hi) ^ axr) << 4;
  const int chx1 = ((4 + hi) ^ axr) << 4;
  const int abase = wr*16384 + fr*128;                         // + m*2048 + chx
  const int bbase = 32768 + (wc>>1)*16384 + ((wc&1)*64 + fr)*128;  // + n*2048 + chx

#define RA(BUF,M,KK) (*(const bf16x8*)(smem + (BUF)*65536 + abase + (M)*2048 + ((KK)?chx1:chx0)))
#define RB(BUF,N,KK) (*(const bf16x8*)(smem + (BUF)*65536 + bbase + (N)*2048 + ((KK)?chx1:chx0)))

#define SGA(BUF,H,T) do{ \
    const bf16_t* p_ = (H) ? ApS1 : ApS0; \
    lds_load16(p_ + (size_t)(T)*AKT,       smem + (BUF)*65536 + (H)*16384 + tid*16); \
    lds_load16(p_ + (size_t)(T)*AKT + AJS, smem + (BUF)*65536 + (H)*16384 + 8192 + tid*16); \
  }while(0)
#define SGB(BUF,H,T) do{ \
    const bf16_t* p_ = (H) ? BpS1 : BpS0; \
    lds_load16(p_ + (size_t)(T)*64,       smem + (BUF)*65536 + 32768 + (H)*16384 + tid*16); \
    lds_load16(p_ + (size_t)(T)*64 + BJS, smem + (BUF)*65536 + 32768 + (H)*16384 + 8192 + tid*16); \
  }while(0)

#define SBR() __builtin_amdgcn_sched_barrier(0)
#define BARX() do{ SBR(); __builtin_amdgcn_s_barrier(); SBR(); }while(0)
#define LG0() do{ asm volatile("s_waitcnt lgkmcnt(0)":::"memory"); SBR(); }while(0)
#define VMW4() do{ asm volatile("s_waitcnt vmcnt(4)":::"memory"); SBR(); }while(0)
#define VMW0() do{ asm volatile("s_waitcnt vmcnt(0)":::"memory"); SBR(); }while(0)

  f32x4 acc[8][4];
  #pragma unroll
  for (int m = 0; m < 8; ++m)
    #pragma unroll
    for (int n = 0; n < 4; ++n) acc[m][n] = f32x4{0.f,0.f,0.f,0.f};

  bf16x8 bfr00, bfr01, bfr10, bfr11, bfr20, bfr21, bfr30, bfr31;

#define PHASE(BUF, Q, STAGES, ENDV) do{ \
    if ((Q) == 0) { \
      bfr00 = RB(BUF,0,0); bfr01 = RB(BUF,0,1); \
      bfr10 = RB(BUF,1,0); bfr11 = RB(BUF,1,1); \
      bfr20 = RB(BUF,2,0); bfr21 = RB(BUF,2,1); \
      bfr30 = RB(BUF,3,0); bfr31 = RB(BUF,3,1); \
    } \
    bf16x8 a00 = RA(BUF,2*(Q)+0,0), a01 = RA(BUF,2*(Q)+0,1); \
    bf16x8 a10 = RA(BUF,2*(Q)+1,0), a11 = RA(BUF,2*(Q)+1,1); \
    STAGES; \
    BARX(); LG0(); \
    __builtin_amdgcn_s_setprio(1); \
    acc[2*(Q)+0][0]=MFMA16(a00,bfr00,acc[2*(Q)+0][0]); acc[2*(Q)+0][0]=MFMA16(a01,bfr01,acc[2*(Q)+0][0]); \
    acc[2*(Q)+0][1]=MFMA16(a00,bfr10,acc[2*(Q)+0][1]); acc[2*(Q)+0][1]=MFMA16(a01,bfr11,acc[2*(Q)+0][1]); \
    acc[2*(Q)+0][2]=MFMA16(a00,bfr20,acc[2*(Q)+0][2]); acc[2*(Q)+0][2]=MFMA16(a01,bfr21,acc[2*(Q)+0][2]); \
    acc[2*(Q)+0][3]=MFMA16(a00,bfr30,acc[2*(Q)+0][3]); acc[2*(Q)+0][3]=MFMA16(a01,bfr31,acc[2*(Q)+0][3]); \
    acc[2*(Q)+1][0]=MFMA16(a10,bfr00,acc[2*(Q)+1][0]); acc[2*(Q)+1][0]=MFMA16(a11,bfr01,acc[2*(Q)+1][0]); \
    acc[2*(Q)+1][1]=MFMA16(a10,bfr10,acc[2*(Q)+1][1]); acc[2*(Q)+1][1]=MFMA16(a11,bfr11,acc[2*(Q)+1][1]); \
    acc[2*(Q)+1][2]=MFMA16(a10,bfr20,acc[2*(Q)+1][2]); acc[2*(Q)+1][2]=MFMA16(a11,bfr21,acc[2*(Q)+1][2]); \
    acc[2*(Q)+1][3]=MFMA16(a10,bfr30,acc[2*(Q)+1][3]); acc[2*(Q)+1][3]=MFMA16(a11,bfr31,acc[2*(Q)+1][3]); \
    __builtin_amdgcn_s_setprio(0); SBR(); \
    ENDV; \
    BARX(); \
  }while(0)

  // prologue: tile 0 (all 4 halves) -> buf0; B(1) -> buf1. 12 loads/thread.
  SGA(0,0,0); SGA(0,1,0); SGB(0,0,0); SGB(0,1,0); SGB(1,0,1); SGB(1,1,1);
  VMW4(); BARX();

  #pragma unroll 1
  for (int i = 0; i < 5; ++i) {
    const int t0 = 2*i;
    PHASE(0,0, { SGA(1,0,t0+1); },                     );
    PHASE(0,1, { SGA(1,1,t0+1); SGB(0,0,t0+2); },      );
    PHASE(0,2, { SGB(0,1,t0+2); },                     );
    PHASE(0,3, { },                                    VMW4());
    PHASE(1,0, { SGA(0,0,t0+2); },                     );
    PHASE(1,1, { SGA(0,1,t0+2); },                     );
    PHASE(1,2, { SGB(1,0,t0+3); },                     );
    PHASE(1,3, { SGB(1,1,t0+3); },                     VMW4());
  }
  // peeled final iteration: tiles 10 (buf0), 11 (buf1); only A(11) left to stage.
  PHASE(0,0, { SGA(1,0,11); },  );
  PHASE(0,1, { SGA(1,1,11); },  );
  PHASE(0,2, { },               );
  PHASE(0,3, { },               VMW0());
  PHASE(1,0, { },               );
  PHASE(1,1, { },               );
  PHASE(1,2, { },               );
  PHASE(1,3, { },               );

#undef PHASE
#undef SGA
#undef SGB
#undef RA
#undef RB
#undef VMW4
#undef VMW0
#undef LG0
#undef BARX
#undef SBR

  // ---------------------------------------------------------------- epilogue
  // C/D frag layout: row = wr*128 + m*16 + (lane>>4)*4 + j, col = wc*64 + n*16 + fr
  if (MODE == 3) {
    #pragma unroll
    for (int n = 0; n < 4; ++n) {
      const int gc = colBase + wc*64 + n*16 + fr;
      const float bb = bias[gc];
      #pragma unroll
      for (int m = 0; m < 8; ++m) {
        const int gr = rowBase + wr*128 + m*16 + ((lane >> 4) << 2);
        #pragma unroll
        for (int j = 0; j < 4; ++j)
          Cout[(size_t)(gr + j)*C_ + gc] = acc[m][n][j] + bb;
      }
    }
  } else {
    __syncthreads();                       // main-loop LDS dead; reuse
    bf16_t* tile = (bf16_t*)smem;          // [64 cols][pitch 260 rows] = 33.3 KB
    const int s = colBase / C_;            // 0=q 1=k 2=v (uniform per block)
    #pragma unroll 1
    for (int ch = 0; ch < 4; ++ch) {       // 64-col chunks of the 256-wide block
      if (ch) __syncthreads();
      if (wc == ch) {
        #pragma unroll
        for (int n = 0; n < 4; ++n) {
          const int cl = n*16 + fr;                        // 0..63
          const float bb = bias[colBase + ch*64 + cl];
          #pragma unroll
          for (int m = 0; m < 8; ++m) {
            const int r0 = wr*128 + m*16 + ((lane >> 4) << 2);
            bf16x4 hv;
            hv[0]=(bf16_t)(acc[m][n][0]+bb); hv[1]=(bf16_t)(acc[m][n][1]+bb);
            hv[2]=(bf16_t)(acc[m][n][2]+bb); hv[3]=(bf16_t)(acc[m][n][3]+bb);
            *(bf16x4*)&tile[cl*260 + r0] = hv;
          }
        }
      }
      __syncthreads();
      const int gcol0 = colBase + ch*64;
      if (s == 0) {
        // q: row-major (b,h,n,d); chunk = exactly one head
        const int h = gcol0 >> 6;
        const int r = tid >> 1, hh = tid & 1;
        bf16_t* dst = qh + (((size_t)b*H_ + h)*N_ + nn0 + r)*D_ + hh*32;
        #pragma unroll
        for (int i0 = 0; i0 < 32; i0 += 8) {
          bf16x8 vv;
          #pragma unroll
          for (int i = 0; i < 8; ++i) vv[i] = tile[(hh*32 + i0 + i)*260 + r];
          *(bf16x8*)&dst[i0] = vv;
        }
      } else {
        // k/v: (b,h,d,n); chunk = one head, d = col-local
        const int rem = gcol0 - s*C_;
        const int h = rem >> 6;
        const int d = tid >> 3, nq = (tid & 7)*32;
        bf16_t* dst = (s == 1 ? kthi : vthi)
                      + (((size_t)b*H_ + h)*D_ + d)*N_ + nn0 + nq;
        #pragma unroll
        for (int i0 = 0; i0 < 32; i0 += 8)
          *(bf16x8*)&dst[i0] = *(const bf16x8*)&tile[d*260 + nq + i0];
      }
    }
  }
}

// ---------------------------------------------------------------- stage 2: logits + softmax
// attnT[bh][e][d] = P[d][e], P = softmax_e( sum_n kt[d][n]*vt[e][n] / 8 )
__global__ __launch_bounds__(256, 2)
void attn_softmax_k(const bf16_t* __restrict__ kthi, const bf16_t* __restrict__ vthi,
                    bf16_t* __restrict__ attnT)
{
  __shared__ float tile[64][65];
  __shared__ float invs[64];
  const int bh = blockIdx.x;
  const int tid = threadIdx.x, wave = tid >> 6, lane = tid & 63;
  const int fr = lane & 15, fo = (lane >> 4) * 8;
  const size_t base = (size_t)bh * D_ * N_;
  f32x4 acc[4][4] = {{0.f,0.f,0.f,0.f}};
  const int k0lo = wave * 256;   // split-K across 4 waves
  #pragma unroll 1
  for (int k0 = k0lo; k0 < k0lo + 256; k0 += 32) {
    bf16x8 ah[4], bhv[4];
    #pragma unroll
    for (int m = 0; m < 4; ++m)
      ah[m] = *(const bf16x8*)&kthi[base + (size_t)(m*16 + fr)*N_ + k0 + fo];
    #pragma unroll
    for (int n = 0; n < 4; ++n)
      bhv[n] = *(const bf16x8*)&vthi[base + (size_t)(n*16 + fr)*N_ + k0 + fo];
    #pragma unroll
    for (int m = 0; m < 4; ++m)
      #pragma unroll
      for (int n = 0; n < 4; ++n)
        acc[m][n] = MFMA16(ah[m], bhv[n], acc[m][n]);
  }
  // cross-wave reduce into LDS
  for (int w = 0; w < 4; ++w) {
    if (wave == w) {
      #pragma unroll
      for (int m = 0; m < 4; ++m)
        #pragma unroll
        for (int n = 0; n < 4; ++n) {
          const int row = m*16 + ((lane >> 4) << 2);
          const int col = n*16 + fr;
          #pragma unroll
          for (int j = 0; j < 4; ++j) {
            if (w == 0) tile[row+j][col]  = acc[m][n][j];
            else        tile[row+j][col] += acc[m][n][j];
          }
        }
    }
    __syncthreads();
  }
  // row softmax (scale 1/8), one thread per row d
  if (tid < 64) {
    float mx = -3.0e38f;
    #pragma unroll
    for (int c = 0; c < 64; ++c) mx = fmaxf(mx, tile[tid][c]);
    mx *= 0.125f;
    float ssum = 0.f;
    #pragma unroll
    for (int c = 0; c < 64; ++c) {
      const float ev = __expf(tile[tid][c]*0.125f - mx);
      tile[tid][c] = ev;
      ssum += ev;
    }
    invs[tid] = 1.0f / ssum;
  }
  __syncthreads();
  // transposed write: thread e writes attnT[e][0..63] contiguous
  if (tid < 64) {
    bf16_t* ao = attnT + (size_t)bh * D_ * D_ + tid * D_;
    #pragma unroll
    for (int d0 = 0; d0 < 64; d0 += 8) {
      bf16x8 vv;
      #pragma unroll
      for (int i = 0; i < 8; ++i) vv[i] = (bf16_t)(tile[d0+i][tid] * invs[d0+i]);
      *(bf16x8*)&ao[d0] = vv;
    }
  }
}

// ---------------------------------------------------------------- stage 3: W' compose
// w2t[b][j][h*64+e] = sum_d woutT[j][h*64+d] * attnT[bh][e][d]
// grid (6, B*H), 256 threads (4 waves x 32 j-rows each)
__global__ __launch_bounds__(256, 2)
void compose_w2(const bf16_t* __restrict__ woutT, const bf16_t* __restrict__ attnT,
                bf16_t* __restrict__ w2t)
{
  const int jb = blockIdx.x;
  const int bh = blockIdx.y;
  const int b = bh / H_, h = bh - b*H_;
  const int tid = threadIdx.x, wave = tid >> 6, lane = tid & 63;
  const int fr = lane & 15, fo = (lane >> 4) * 8;
  const bf16_t* at = attnT + (size_t)bh * D_ * D_;
  f32x4 acc[2][4] = {{0.f,0.f,0.f,0.f}};
  #pragma unroll
  for (int kk = 0; kk < 2; ++kk) {
    bf16x8 af[2], bfv[4];
    #pragma unroll
    for (int m = 0; m < 2; ++m)
      af[m] = *(const bf16x8*)&woutT[(size_t)(jb*128 + wave*32 + m*16 + fr)*C_ + h*64 + kk*32 + fo];
    #pragma unroll
    for (int n = 0; n < 4; ++n)
      bfv[n] = *(const bf16x8*)&at[(n*16 + fr)*64 + kk*32 + fo];
    #pragma unroll
    for (int m = 0; m < 2; ++m)
      #pragma unroll
      for (int n = 0; n < 4; ++n)
        acc[m][n] = MFMA16(af[m], bfv[n], acc[m][n]);
  }
  bf16_t* wb = w2t + (size_t)b * C_ * C_;
  #pragma unroll
  for (int m = 0; m < 2; ++m) {
    const int j = jb*128 + wave*32 + m*16 + ((lane >> 4) << 2);
    #pragma unroll
    for (int n = 0; n < 4; ++n) {
      const int e = n*16 + fr;
      #pragma unroll
      for (int jj = 0; jj < 4; ++jj)
        wb[(size_t)(j + jj)*C_ + h*64 + e] = (bf16_t)acc[m][n][jj];
    }
  }
}

// ---------------------------------------------------------------- launcher
extern "C" void kernel_launch(void* const* d_in, const int* in_sizes, int n_in,
                              void* d_out, int out_size, void* d_ws, size_t ws_size,
                              hipStream_t stream)
{
  (void)in_sizes; (void)n_in; (void)out_size;
  const float* x     = (const float*)d_in[0];
  const float* w_qkv = (const float*)d_in[1];
  const float* b_qkv = (const float*)d_in[2];
  const float* w_out = (const float*)d_in[3];
  const float* b_out = (const float*)d_in[4];
  float* out = (float*)d_out;

  const size_t sz_xb   = (size_t)M_*C_*2;        // 50.3 MB
  const size_t sz_wq   = (size_t)TC_*C_*2;       //  3.5 MB
  const size_t sz_wo   = (size_t)C_*C_*2;        //  1.2 MB
  const size_t sz_qh   = (size_t)B_*H_*N_*D_*2;  // 50.3 MB
  const size_t sz_kv   = (size_t)B_*H_*D_*N_*2;  // 50.3 MB each
  const size_t sz_attn = (size_t)B_*H_*D_*D_*2;  //  3.1 MB

  char* p = (char*)d_ws;
  bf16_t* xb    = (bf16_t*)p; p += sz_xb;
  bf16_t* wqkvT = (bf16_t*)p; p += sz_wq;
  bf16_t* woutT = (bf16_t*)p; p += sz_wo;
  bf16_t* qh    = (bf16_t*)p; p += sz_qh;
  bf16_t* kthi  = (bf16_t*)p; p += sz_kv;
  bf16_t* vthi  = (bf16_t*)p; p += sz_kv;
  bf16_t* attnT = (bf16_t*)p; p += sz_attn;
  const size_t base_need = (size_t)(p - (char*)d_ws);
  // W' (32 x 768 x 768 bf16 = 37.7 MB) aliases xb (50.3 MB), dead after GEMM1
  bf16_t* w2t = xb;

  if (ws_size < base_need) return;   // leaves poison -> distinctive failure

  cvt_bf16<<<dim3((M_*C_)/2048), 256, 0, stream>>>(x, xb, M_*C_);
  transpose_cvt<<<dim3(TC_/32, C_/32), 256, 0, stream>>>(w_qkv, wqkvT, C_, TC_);
  transpose_cvt<<<dim3(C_/32,  C_/32), 256, 0, stream>>>(w_out, woutT, C_, C_);

  // GEMM1: qkv projection with scatter epilogue. grid = 9 x 128 = 1152 (8 | 1152)
  gemm_bt<1><<<dim3((TC_/256)*(M_/256)), 512, 0, stream>>>(
      xb, wqkvT, b_qkv, nullptr, qh, kthi, vthi, TC_/256);

  attn_softmax_k<<<dim3(B_*H_), 256, 0, stream>>>(kthi, vthi, attnT);

  compose_w2<<<dim3(C_/128, B_*H_), 256, 0, stream>>>(woutT, attnT, w2t);

  // GEMM2: out = qh(gathered) @ W'_b + b_out. grid = 3 x 128 = 384 (8 | 384)
  gemm_bt<3><<<dim3((C_/256)*(M_/256)), 512, 0, stream>>>(
      qh, w2t, b_out, out, nullptr, nullptr, nullptr, C_/256);
}